// Round 15
// baseline (74.573 us; speedup 1.0000x reference)
//
#include <hip/hip_runtime.h>
#include <hip/hip_bf16.h>
#include <stdint.h>

// Problem: B=16384, D=256, E=16, K=4, C=10
// out = [market_probs (B*C) | all_probs (E*B*C) | gate_probs (B*E)], fp32
// ws layout (bytes):
//   xk   bf16 [128 mt][8 kt][128 s][32 k] @ 0        (8388608)  k-major xhat
//   w1km bf16 [E][8 kt][256 n][32 k]      @ 8388608  (2097152)  k-major ln_g*w1
//   w2t  bf16 [E][16 c][256 h]            @ 10485760 (131072)   zero-padded c=10..15
//   b1p  f32  [E][256]                    @ 10616832 (16384)    b1 + ln_b @ w1 (direct)
//   tki  int  [B][4]                      @ 10633216 (262144)
//   tkw  f32  [B][4]                      @ 10895360 (262144)

typedef __bf16 bf16;
typedef __bf16 bf16x8 __attribute__((ext_vector_type(8)));
typedef __bf16 bf16x4 __attribute__((ext_vector_type(4)));
typedef float  f32x4  __attribute__((ext_vector_type(4)));

#define XK_OFF   0UL
#define W1T_OFF  8388608UL
#define W2T_OFF  10485760UL
#define B1P_OFF  10616832UL
#define TKI_OFF  10633216UL
#define TKW_OFF  10895360UL

#define APROBS_OFF 163840UL
#define GATE_OFF   2785280UL

#define LOG2E 1.4426950408889634f

__device__ __forceinline__ void gl_lds16(const void* g, void* l) {
  __builtin_amdgcn_global_load_lds((const __attribute__((address_space(1))) void*)g,
                                   (__attribute__((address_space(3))) void*)l, 16, 0, 0);
}

// pack two f32 -> one u32 of 2x bf16 (low = a, high = b)
__device__ __forceinline__ uint32_t cvt_pk_bf16(float a, float b) {
  uint32_t r;
  asm("v_cvt_pk_bf16_f32 %0, %1, %2" : "=v"(r) : "v"(a), "v"(b));
  return r;
}

// sigmoid-form GELU: x * sigmoid(1.702 x) = x / (1 + exp2(-2.45541 x));
// max abs err vs exact (erf) gelu ~5e-3 for |x|<=1.5 (h_pre std ~0.32).
__device__ __forceinline__ float gelu_f(float x) {
  float e = __builtin_amdgcn_exp2f(-2.45541f * x);
  return x * __builtin_amdgcn_rcpf(e + 1.0f);
}

// ---------------- fused pre-pass: w1km+b1p (64) | w2t (16) | ln+router+xk (1024 x 4 iters) ------
__global__ __launch_bounds__(256) void k_pre(const float* __restrict__ feat,
                                             const float* __restrict__ rw,
                                             const float* __restrict__ rb,
                                             const float* __restrict__ ln_g,
                                             const float* __restrict__ ln_b,
                                             const float* __restrict__ b1,
                                             const float* __restrict__ w1,
                                             const float* __restrict__ w2,
                                             float* __restrict__ out,
                                             char* __restrict__ ws) {
  __shared__ __align__(16) char sm[20736];
  const int bid = blockIdx.x;
  const int t = threadIdx.x;

  if (bid < 64) {  // w1km[e][kt][n][32] = ln_g*w1 (k-major); b1p = b1 + ln_b@w1, DIRECT write
    float (*tile)[68] = (float(*)[68])sm;
    const int e = bid >> 2, nt = bid & 3;
    const int rn = t >> 2, ks = t & 3;
    const int n = nt * 64 + rn;
    bf16* base = (bf16*)(ws + W1T_OFF) + (size_t)e * 65536;
    float pb = 0.f;
#pragma unroll
    for (int kt = 0; kt < 4; ++kt) {
      {  // load 64k x 64n fp32 tile
        const float* src = w1 + ((size_t)e * 256 + kt * 64 + rn) * 256 + nt * 64 + ks * 16;
#pragma unroll
        for (int j = 0; j < 4; ++j) {
          float4 v = *(const float4*)(src + j * 4);
          *(float4*)(&tile[rn][ks * 16 + j * 4]) = v;
        }
      }
      __syncthreads();
      {  // transpose+scale -> w1km; accumulate ln_b @ w1
#pragma unroll
        for (int j = 0; j < 4; ++j) {
          int kc = ks * 16 + j * 4;               // within 64-k tile
          int k0 = kt * 64 + kc;                  // global k
          float4 g4 = *(const float4*)(ln_g + e * 256 + k0);
          float4 l4 = *(const float4*)(ln_b + e * 256 + k0);
          float t0 = tile[kc + 0][rn], t1 = tile[kc + 1][rn];
          float t2 = tile[kc + 2][rn], t3 = tile[kc + 3][rn];
          bf16x4 o;
          o[0] = (bf16)(t0 * g4.x);
          o[1] = (bf16)(t1 * g4.y);
          o[2] = (bf16)(t2 * g4.z);
          o[3] = (bf16)(t3 * g4.w);
          pb += l4.x * t0 + l4.y * t1 + l4.z * t2 + l4.w * t3;
          *(bf16x4*)(base + (k0 >> 5) * 8192 + n * 32 + (k0 & 31)) = o;
        }
      }
      __syncthreads();  // tile reads done before next kt overwrites
    }
    pb += __shfl_xor(pb, 1);
    pb += __shfl_xor(pb, 2);
    if (ks == 0)
      ((float*)(ws + B1P_OFF))[e * 256 + n] = pb + b1[e * 256 + n];
  } else if (bid < 80) {  // w2t[e][c][h], c padded to 16
    const int e = bid - 64;
    const int c = t >> 4, hs = t & 15;
    bf16* dst = (bf16*)(ws + W2T_OFF) + (size_t)e * 4096 + c * 256 + hs * 16;
#pragma unroll
    for (int j4 = 0; j4 < 4; ++j4) {
      bf16x4 o;
#pragma unroll
      for (int j = 0; j < 4; ++j) {
        int h = hs * 16 + j4 * 4 + j;
        float v = (c < 10) ? w2[((size_t)e * 256 + h) * 10 + c] : 0.0f;
        o[j] = (bf16)v;
      }
      *(bf16x4*)(dst + j4 * 4) = o;
    }
  } else {  // LN stats + xk(bf16 k-major) + router softmax + top-4; 16 rows/block (4 iters)
    float (*rwt)[260] = (float(*)[260])sm;
    float (*xrow)[256] = (float(*)[256])(sm + 16640);
    const int w = t >> 6, l = t & 63;
    const int e = l & 15, q = l >> 4;

    // stage transposed router weights ONCE per block (amortized over 16 rows)
#pragma unroll
    for (int i = 0; i < 16; ++i) {
      int idx = t + 256 * i;
      rwt[idx & 15][idx >> 4] = rw[idx];
    }
    __syncthreads();

    for (int it = 0; it < 4; ++it) {
      const int b = (bid - 80) * 16 + it * 4 + w;

      float4 x4 = *(const float4*)(feat + (size_t)b * 256 + l * 4);
      *(float4*)(&xrow[w][l * 4]) = x4;

      float s = x4.x + x4.y + x4.z + x4.w;
      float s2 = x4.x * x4.x + x4.y * x4.y + x4.z * x4.z + x4.w * x4.w;
#pragma unroll
      for (int off = 1; off < 64; off <<= 1) {
        s += __shfl_xor(s, off);
        s2 += __shfl_xor(s2, off);
      }
      float mu = s * (1.0f / 256.0f);
      float var = s2 * (1.0f / 256.0f) - mu * mu;
      float rstd = __builtin_amdgcn_rsqf(var + 1e-5f);
      bf16x4 hb;
      hb[0] = (bf16)((x4.x - mu) * rstd);
      hb[1] = (bf16)((x4.y - mu) * rstd);
      hb[2] = (bf16)((x4.z - mu) * rstd);
      hb[3] = (bf16)((x4.w - mu) * rstd);
      // xk[mt][kt][s][32k]: mt=b>>7, s=b&127, k=4l..4l+3
      *(bf16x4*)((bf16*)(ws + XK_OFF) + ((size_t)(b >> 7) * 32768) + (l >> 3) * 4096 +
                 (b & 127) * 32 + (l & 7) * 4) = hb;

      // gate logits: lane owns expert e, quarter q of D (xrow is per-wave; no barrier)
      float g = 0.f;
#pragma unroll
      for (int i = 0; i < 16; ++i) {
        float4 xv = *(const float4*)(&xrow[w][q * 64 + i * 4]);
        float4 wv = *(const float4*)(&rwt[e][q * 64 + i * 4]);
        g += xv.x * wv.x + xv.y * wv.y + xv.z * wv.z + xv.w * wv.w;
      }
      g += __shfl_xor(g, 16);
      g += __shfl_xor(g, 32);
      g += rb[e];

      float m = g;
#pragma unroll
      for (int off = 1; off < 16; off <<= 1) m = fmaxf(m, __shfl_xor(m, off));
      float p = __builtin_amdgcn_exp2f((g - m) * LOG2E);
      float sum = p;
#pragma unroll
      for (int off = 1; off < 16; off <<= 1) sum += __shfl_xor(sum, off);
      float prob = p * __builtin_amdgcn_rcpf(sum);
      if (q == 0) out[GATE_OFF + (size_t)b * 16 + e] = prob;

      float pv[16];
#pragma unroll
      for (int i = 0; i < 16; ++i) pv[i] = __shfl(prob, i);
      int idxk[4];
      float valk[4];
#pragma unroll
      for (int k = 0; k < 4; ++k) {
        float best = pv[0];
        int bi = 0;
#pragma unroll
        for (int i = 1; i < 16; ++i) {
          if (pv[i] > best) { best = pv[i]; bi = i; }
        }
        valk[k] = best;
        idxk[k] = bi;
#pragma unroll
        for (int i = 0; i < 16; ++i) pv[i] = (i == bi) ? -1.0f : pv[i];
      }
      float wsum = valk[0] + valk[1] + valk[2] + valk[3];
      float rn2 = __builtin_amdgcn_rcpf(wsum);
      if (l == 0) {
        int4 iv = {idxk[0], idxk[1], idxk[2], idxk[3]};
        float4 wv = {valk[0] * rn2, valk[1] * rn2, valk[2] * rn2, valk[3] * rn2};
        *(int4*)(ws + TKI_OFF + (size_t)b * 16) = iv;
        *(float4*)(ws + TKW_OFF + (size_t)b * 16) = wv;
      }
    }
  }
}

// ---------------- main fused: GEMM1 -> GELU -> reg-GEMM2 -> reduce -> softmax
// BM=128 s x BN=256 n; 2048 blocks (XCD-chunked, expert-fast), 512 threads,
// 8 waves = 4 n-quarters (wnb) x 2 sample-halves (wsb); wave tile 64n x 64s.
// k-loop identical to r8/r10/r12 (best known). GEMM2 in registers; w2 B-frags
// direct from L2. NO market fusion (r13 lesson: per-thread tki/tkw loads +
// 655K atomics on the block tail cost +18us vs a 4us k_market dispatch).
// LDS: W dbuf 2x16K @0 ; X dbuf 2x8K @32768 ; partials 32K @0 (overlay). 49152 B.
// launch_bounds(512,4): allocator not pinched (r11 lesson: 85-reg cap -> spill).
// Softmax max-pass skipped (|logit| < ~1, exp2 safe).
__global__ __launch_bounds__(512, 4) void k_moe(const char* __restrict__ ws,
                                                const float* __restrict__ b2g,
                                                float* __restrict__ out) {
  __shared__ __align__(16) char smem[49152];
  const int lin = blockIdx.x;
  const int e = (lin >> 3) & 15;                 // expert-fast within an XCD chunk
  const int mt = (lin & 7) * 16 + (lin >> 7);    // each XCD owns 16 contiguous mtiles
  const int m0 = mt * 128;
  const int t = threadIdx.x;
  const int wid = t >> 6, l = t & 63;
  const int lq = l >> 4, lr = l & 15;
  const int wnb = wid >> 1;   // n-quarter 0..3 (64 n each)
  const int wsb = wid & 1;    // sample-half 0..1 (64 samples each)

  const uint16_t* xk = (const uint16_t*)(ws + XK_OFF) + (size_t)mt * 32768;   // [kt][128 s][32 k]
  const uint16_t* w1km = (const uint16_t*)(ws + W1T_OFF) + (size_t)e * 65536; // [kt][256 n][32 k]
  const uint16_t* w2t = (const uint16_t*)(ws + W2T_OFF) + (size_t)e * 4096;
  const float* b1p = (const float*)(ws + B1P_OFF) + e * 256;

  // staging source permutation: LDS 16B-unit u -> row 2p+hf, k-slot (sl^(p&3))
  const int pn = t >> 3, hf = (t >> 2) & 1, sl = t & 3;
  const int srcoff = (2 * pn + hf) * 32 + ((sl ^ (pn & 3)) * 8);
  const uint16_t* sW = w1km + srcoff;   // + kt*8192 ; second half + 4096
  const uint16_t* sX = xk + srcoff;     // + kt*4096

  // prologue: kt=0 W (16K) + X (8K) into buf0
  gl_lds16(sW, smem + wid * 1024);
  gl_lds16(sW + 4096, smem + 8192 + wid * 1024);
  gl_lds16(sX, smem + 32768 + wid * 1024);

  // fragment LDS offsets: row r -> p=r>>1 (pair), byte = p*128 + (r&1)*64 + ((lq^(p&3))<<4)
  const int pr = lr >> 1;
  const int fsw = (lr & 1) * 64 + ((lq ^ (pr & 3)) << 4);
  const int aoffb = (wnb * 32 + pr) * 128 + fsw;            // + buf*16384 + mi*1024
  const int xoffb = (wsb * 32 + pr) * 128 + fsw;            // + 32768 + buf*8192 + nj*1024

  f32x4 zz = {0.f, 0.f, 0.f, 0.f};
  f32x4 acc[4][4];  // [mi: n][nj: sample]
#pragma unroll
  for (int mi = 0; mi < 4; ++mi)
#pragma unroll
    for (int nj = 0; nj < 4; ++nj) acc[mi][nj] = zz;

  __syncthreads();
#pragma unroll
  for (int kt = 0; kt < 8; ++kt) {
    const int buf = kt & 1;
    // STAGE next kt first: reads+MFMA below cover the DMA before the drain
    if (kt < 7) {
      const uint16_t* a = sW + (kt + 1) * 8192;
      char* dW = smem + (buf ^ 1) * 16384 + wid * 1024;
      gl_lds16(a, dW);
      gl_lds16(a + 4096, dW + 8192);
      gl_lds16(sX + (kt + 1) * 4096, smem + 32768 + (buf ^ 1) * 8192 + wid * 1024);
    }
    bf16x8 af[4], xf[4];
#pragma unroll
    for (int mi = 0; mi < 4; ++mi)
      af[mi] = *(const bf16x8*)(smem + buf * 16384 + aoffb + mi * 1024);
#pragma unroll
    for (int nj = 0; nj < 4; ++nj)
      xf[nj] = *(const bf16x8*)(smem + 32768 + buf * 8192 + xoffb + nj * 1024);
    __builtin_amdgcn_s_setprio(1);
#pragma unroll
    for (int mi = 0; mi < 4; ++mi)
#pragma unroll
      for (int nj = 0; nj < 4; ++nj)
        acc[mi][nj] = __builtin_amdgcn_mfma_f32_16x16x32_bf16(af[mi], xf[nj], acc[mi][nj], 0, 0, 0);
    __builtin_amdgcn_s_setprio(0);
    __syncthreads();  // next tile landed; all reads of buf done
  }

  // w2 B-fragments DIRECT from L2: lane -> w2t[c=lr][wnb*64 + mi*16 + lq*4 .. +3]
  const uint16_t* w2l = w2t + lr * 256 + wnb * 64 + lq * 4;
  uint2 w2f[4];
#pragma unroll
  for (int mi = 0; mi < 4; ++mi)
    w2f[mi] = *(const uint2*)(w2l + mi * 16);
  uint4 ub0 = {w2f[0].x, w2f[0].y, w2f[1].x, w2f[1].y};  // k-frag for mi 0,1
  uint4 ub1 = {w2f[2].x, w2f[2].y, w2f[3].x, w2f[3].y};  // k-frag for mi 2,3

  float4 bn[4];
#pragma unroll
  for (int mi = 0; mi < 4; ++mi)
    bn[mi] = *(const float4*)(b1p + wnb * 64 + mi * 16 + lq * 4);

  // GELU in regs -> packed A-frags -> 2 MFMAs per nj (64n partial of D[s][c])
  f32x4 acc2[4];
#pragma unroll
  for (int nj = 0; nj < 4; ++nj) {
    uint32_t pk[8];
#pragma unroll
    for (int mi = 0; mi < 4; ++mi) {
      float g0 = gelu_f(acc[mi][nj][0] + bn[mi].x);
      float g1 = gelu_f(acc[mi][nj][1] + bn[mi].y);
      float g2 = gelu_f(acc[mi][nj][2] + bn[mi].z);
      float g3 = gelu_f(acc[mi][nj][3] + bn[mi].w);
      pk[mi * 2] = cvt_pk_bf16(g0, g1);
      pk[mi * 2 + 1] = cvt_pk_bf16(g2, g3);
    }
    uint4 ua0 = {pk[0], pk[1], pk[2], pk[3]};
    uint4 ua1 = {pk[4], pk[5], pk[6], pk[7]};
    f32x4 a2 = zz;
    a2 = __builtin_amdgcn_mfma_f32_16x16x32_bf16(__builtin_bit_cast(bf16x8, ua0),
                                                 __builtin_bit_cast(bf16x8, ub0), a2, 0, 0, 0);
    a2 = __builtin_amdgcn_mfma_f32_16x16x32_bf16(__builtin_bit_cast(bf16x8, ua1),
                                                 __builtin_bit_cast(bf16x8, ub1), a2, 0, 0, 0);
    acc2[nj] = a2;
  }

  // partial exchange @0 (overlays W dbuf): [g = wsb*4+nj][wnb][16 s][16 c] f32
  const int pswz = (lq ^ ((lr >> 1) & 3)) << 4;
  {
    const int pbase = wnb * 1024 + lr * 64 + pswz;
#pragma unroll
    for (int nj = 0; nj < 4; ++nj)
      *(f32x4*)(smem + pbase + (wsb * 4 + nj) * 4096) = acc2[nj];
  }
  __syncthreads();

  // reduce own group g = wsb*4+wnb over the 4 wnb-partials; softmax (no max pass:
  // |logit| < ~1); store all_probs
  {
    const int rbase = (wsb * 4 + wnb) * 4096 + lr * 64 + pswz;
    f32x4 r0 = *(const f32x4*)(smem + rbase);
    f32x4 r1 = *(const f32x4*)(smem + rbase + 1024);
    f32x4 r2 = *(const f32x4*)(smem + rbase + 2048);
    f32x4 r3 = *(const f32x4*)(smem + rbase + 3072);
    f32x4 tot;
#pragma unroll
    for (int j = 0; j < 4; ++j) tot[j] = (r0[j] + r1[j]) + (r2[j] + r3[j]);

    const int c = lr;
    float bias2 = (c < 10) ? b2g[e * 10 + c] : 0.0f;
#pragma unroll
    for (int rg = 0; rg < 4; ++rg) {
      float logit = tot[rg] + bias2;
      float ex = (c < 10) ? __builtin_amdgcn_exp2f(logit * LOG2E) : 0.0f;
      float sm = ex;
#pragma unroll
      for (int off = 1; off < 16; off <<= 1) sm += __shfl_xor(sm, off);
      if (c < 10) {
        float pr_ = ex * __builtin_amdgcn_rcpf(sm);
        size_t row = (size_t)e * 16384 + (m0 + wsb * 64 + wnb * 16 + lq * 4 + rg);
        out[APROBS_OFF + row * 10 + c] = pr_;
      }
    }
  }
}

// ---------------- market_probs = sum_k w_k * all_probs[idx_k, b, :] ----------------
__global__ __launch_bounds__(256) void k_market(const char* __restrict__ ws,
                                                float* __restrict__ out) {
  const int b = blockIdx.x * 256 + threadIdx.x;
  int4 id = *(const int4*)(ws + TKI_OFF + (size_t)b * 16);
  float4 wv = *(const float4*)(ws + TKW_OFF + (size_t)b * 16);
  const int ids[4] = {id.x, id.y, id.z, id.w};
  const float wss[4] = {wv.x, wv.y, wv.z, wv.w};
  float m[10];
#pragma unroll
  for (int c = 0; c < 10; ++c) m[c] = 0.f;
#pragma unroll
  for (int k = 0; k < 4; ++k) {
    const float* ap = out + APROBS_OFF + ((size_t)ids[k] * 16384 + b) * 10;
#pragma unroll
    for (int c = 0; c < 10; ++c) m[c] += wss[k] * ap[c];
  }
#pragma unroll
  for (int c = 0; c < 10; ++c) out[(size_t)b * 10 + c] = m[c];
}

extern "C" void kernel_launch(void* const* d_in, const int* in_sizes, int n_in,
                              void* d_out, int out_size, void* d_ws, size_t ws_size,
                              hipStream_t stream) {
  (void)in_sizes; (void)n_in; (void)out_size; (void)ws_size;
  const float* feat = (const float*)d_in[0];
  const float* rw   = (const float*)d_in[1];
  const float* rb   = (const float*)d_in[2];
  const float* ln_g = (const float*)d_in[3];
  const float* ln_b = (const float*)d_in[4];
  const float* w1   = (const float*)d_in[5];
  const float* b1   = (const float*)d_in[6];
  const float* w2   = (const float*)d_in[7];
  const float* b2   = (const float*)d_in[8];
  float* out = (float*)d_out;
  char* ws = (char*)d_ws;

  hipLaunchKernelGGL(k_pre, dim3(1104), dim3(256), 0, stream,
                     feat, rw, rb, ln_g, ln_b, b1, w1, w2, out, ws);
  hipLaunchKernelGGL(k_moe, dim3(2048), dim3(512), 0, stream, ws, b2, out);
  hipLaunchKernelGGL(k_market, dim3(64), dim3(256), 0, stream, ws, out);
}

// Round 16
// 70.798 us; speedup vs baseline: 1.0533x; 1.0533x over previous
//
#include <hip/hip_runtime.h>
#include <hip/hip_bf16.h>
#include <stdint.h>

// Problem: B=16384, D=256, E=16, K=4, C=10
// out = [market_probs (B*C) | all_probs (E*B*C) | gate_probs (B*E)], fp32
// ws layout (bytes):
//   xk   bf16 [128 mt][8 kt][128 s][32 k] @ 0        (8388608)  k-major xhat
//   w1km bf16 [E][8 kt][256 n][32 k]      @ 8388608  (2097152)  k-major ln_g*w1
//   w2t  bf16 [E][16 c][256 h]            @ 10485760 (131072)   zero-padded c=10..15
//   b1p  f32  [E][256]                    @ 10616832 (16384)    b1 + ln_b @ w1 (direct)
//   tki  int  [B][4]                      @ 10633216 (262144)
//   tkw  f32  [B][4]                      @ 10895360 (262144)

typedef __bf16 bf16;
typedef __bf16 bf16x8 __attribute__((ext_vector_type(8)));
typedef __bf16 bf16x4 __attribute__((ext_vector_type(4)));
typedef float  f32x4  __attribute__((ext_vector_type(4)));

#define XK_OFF   0UL
#define W1T_OFF  8388608UL
#define W2T_OFF  10485760UL
#define B1P_OFF  10616832UL
#define TKI_OFF  10633216UL
#define TKW_OFF  10895360UL

#define APROBS_OFF 163840UL
#define GATE_OFF   2785280UL

#define LOG2E 1.4426950408889634f

__device__ __forceinline__ void gl_lds16(const void* g, void* l) {
  __builtin_amdgcn_global_load_lds((const __attribute__((address_space(1))) void*)g,
                                   (__attribute__((address_space(3))) void*)l, 16, 0, 0);
}

// pack two f32 -> one u32 of 2x bf16 (low = a, high = b)
__device__ __forceinline__ uint32_t cvt_pk_bf16(float a, float b) {
  uint32_t r;
  asm("v_cvt_pk_bf16_f32 %0, %1, %2" : "=v"(r) : "v"(a), "v"(b));
  return r;
}

// sigmoid-form GELU: x * sigmoid(1.702 x) = x / (1 + exp2(-2.45541 x));
// max abs err vs exact (erf) gelu ~5e-3 for |x|<=1.5 (h_pre std ~0.32).
__device__ __forceinline__ float gelu_f(float x) {
  float e = __builtin_amdgcn_exp2f(-2.45541f * x);
  return x * __builtin_amdgcn_rcpf(e + 1.0f);
}

// ---------------- fused pre-pass: w1km+b1p (256) | w2t (16) | ln+router+xk (4096) ----------------
__global__ __launch_bounds__(256) void k_pre(const float* __restrict__ feat,
                                             const float* __restrict__ rw,
                                             const float* __restrict__ rb,
                                             const float* __restrict__ ln_g,
                                             const float* __restrict__ ln_b,
                                             const float* __restrict__ b1,
                                             const float* __restrict__ w1,
                                             const float* __restrict__ w2,
                                             float* __restrict__ out,
                                             char* __restrict__ ws) {
  __shared__ __align__(16) char sm[20736];
  const int bid = blockIdx.x;
  const int t = threadIdx.x;

  if (bid < 256) {  // w1km[e][kt][n][32] = ln_g*w1 (k-major), 16-n slice per block (4x
    // parallelism vs r14's 64 blocks); b1p = b1 + ln_b@w1 direct (full k in-block).
    float (*tile)[17] = (float(*)[17])sm;     // [64 k][16 n] +1 pad: reads 2-way max
    const int e = bid >> 4, ng = bid & 15;
    const int lrow = t >> 2, cs = t & 3;      // load phase: row lrow, floats cs*4..+3
    const int rn = t >> 4, ks = t & 15;       // compute phase: n-local rn, k-slice ks
    const int n = ng * 16 + rn;
    bf16* base = (bf16*)(ws + W1T_OFF) + (size_t)e * 65536;
    float pb = 0.f;
#pragma unroll
    for (int kt = 0; kt < 4; ++kt) {
      {  // load 64k x 16n fp32 slice (64B/row, 4 threads per row, coalesced)
        const float* src = w1 + ((size_t)e * 256 + kt * 64 + lrow) * 256 + ng * 16 + cs * 4;
        float4 v = *(const float4*)src;
        tile[lrow][cs * 4 + 0] = v.x;
        tile[lrow][cs * 4 + 1] = v.y;
        tile[lrow][cs * 4 + 2] = v.z;
        tile[lrow][cs * 4 + 3] = v.w;
      }
      __syncthreads();
      {  // transpose+scale -> w1km; accumulate ln_b @ w1
        const int k0 = kt * 64 + ks * 4;
        float4 g4 = *(const float4*)(ln_g + e * 256 + k0);
        float4 l4 = *(const float4*)(ln_b + e * 256 + k0);
        float t0 = tile[ks * 4 + 0][rn], t1 = tile[ks * 4 + 1][rn];
        float t2 = tile[ks * 4 + 2][rn], t3 = tile[ks * 4 + 3][rn];
        bf16x4 o;
        o[0] = (bf16)(t0 * g4.x);
        o[1] = (bf16)(t1 * g4.y);
        o[2] = (bf16)(t2 * g4.z);
        o[3] = (bf16)(t3 * g4.w);
        pb += l4.x * t0 + l4.y * t1 + l4.z * t2 + l4.w * t3;
        *(bf16x4*)(base + (k0 >> 5) * 8192 + n * 32 + (k0 & 31)) = o;
      }
      __syncthreads();  // tile reads done before next kt overwrites
    }
    pb += __shfl_xor(pb, 1);
    pb += __shfl_xor(pb, 2);
    pb += __shfl_xor(pb, 4);
    pb += __shfl_xor(pb, 8);
    if (ks == 0)
      ((float*)(ws + B1P_OFF))[e * 256 + n] = pb + b1[e * 256 + n];
  } else if (bid < 272) {  // w2t[e][c][h], c padded to 16
    const int e = bid - 256;
    const int c = t >> 4, hs = t & 15;
    bf16* dst = (bf16*)(ws + W2T_OFF) + (size_t)e * 4096 + c * 256 + hs * 16;
#pragma unroll
    for (int j4 = 0; j4 < 4; ++j4) {
      bf16x4 o;
#pragma unroll
      for (int j = 0; j < 4; ++j) {
        int h = hs * 16 + j4 * 4 + j;
        float v = (c < 10) ? w2[((size_t)e * 256 + h) * 10 + c] : 0.0f;
        o[j] = (bf16)v;
      }
      *(bf16x4*)(dst + j4 * 4) = o;
    }
  } else {  // LN stats + xk(bf16 k-major) + router softmax + top-4 (r14 form: 4 rows/block)
    float (*rwt)[260] = (float(*)[260])sm;
    float (*xrow)[256] = (float(*)[256])(sm + 16640);
    const int w = t >> 6, l = t & 63;
    const int b = (bid - 272) * 4 + w;

    float4 x4 = *(const float4*)(feat + (size_t)b * 256 + l * 4);

#pragma unroll
    for (int i = 0; i < 16; ++i) {
      int idx = t + 256 * i;
      rwt[idx & 15][idx >> 4] = rw[idx];
    }
    *(float4*)(&xrow[w][l * 4]) = x4;

    float s = x4.x + x4.y + x4.z + x4.w;
    float s2 = x4.x * x4.x + x4.y * x4.y + x4.z * x4.z + x4.w * x4.w;
#pragma unroll
    for (int off = 1; off < 64; off <<= 1) {
      s += __shfl_xor(s, off);
      s2 += __shfl_xor(s2, off);
    }
    float mu = s * (1.0f / 256.0f);
    float var = s2 * (1.0f / 256.0f) - mu * mu;
    float rstd = __builtin_amdgcn_rsqf(var + 1e-5f);
    bf16x4 hb;
    hb[0] = (bf16)((x4.x - mu) * rstd);
    hb[1] = (bf16)((x4.y - mu) * rstd);
    hb[2] = (bf16)((x4.z - mu) * rstd);
    hb[3] = (bf16)((x4.w - mu) * rstd);
    // xk[mt][kt][s][32k]: mt=b>>7, s=b&127, k=4l..4l+3
    *(bf16x4*)((bf16*)(ws + XK_OFF) + ((size_t)(b >> 7) * 32768) + (l >> 3) * 4096 +
               (b & 127) * 32 + (l & 7) * 4) = hb;

    __syncthreads();

    const int e = l & 15, q = l >> 4;
    float g = 0.f;
#pragma unroll
    for (int i = 0; i < 16; ++i) {
      float4 xv = *(const float4*)(&xrow[w][q * 64 + i * 4]);
      float4 wv = *(const float4*)(&rwt[e][q * 64 + i * 4]);
      g += xv.x * wv.x + xv.y * wv.y + xv.z * wv.z + xv.w * wv.w;
    }
    g += __shfl_xor(g, 16);
    g += __shfl_xor(g, 32);
    g += rb[e];

    float m = g;
#pragma unroll
    for (int off = 1; off < 16; off <<= 1) m = fmaxf(m, __shfl_xor(m, off));
    float p = __builtin_amdgcn_exp2f((g - m) * LOG2E);
    float sum = p;
#pragma unroll
    for (int off = 1; off < 16; off <<= 1) sum += __shfl_xor(sum, off);
    float prob = p * __builtin_amdgcn_rcpf(sum);
    if (q == 0) out[GATE_OFF + (size_t)b * 16 + e] = prob;

    float pv[16];
#pragma unroll
    for (int i = 0; i < 16; ++i) pv[i] = __shfl(prob, i);
    int idxk[4];
    float valk[4];
#pragma unroll
    for (int k = 0; k < 4; ++k) {
      float best = pv[0];
      int bi = 0;
#pragma unroll
      for (int i = 1; i < 16; ++i) {
        if (pv[i] > best) { best = pv[i]; bi = i; }
      }
      valk[k] = best;
      idxk[k] = bi;
#pragma unroll
      for (int i = 0; i < 16; ++i) pv[i] = (i == bi) ? -1.0f : pv[i];
    }
    float wsum = valk[0] + valk[1] + valk[2] + valk[3];
    float rn2 = __builtin_amdgcn_rcpf(wsum);
    if (l == 0) {
      int4 iv = {idxk[0], idxk[1], idxk[2], idxk[3]};
      float4 wv = {valk[0] * rn2, valk[1] * rn2, valk[2] * rn2, valk[3] * rn2};
      *(int4*)(ws + TKI_OFF + (size_t)b * 16) = iv;
      *(float4*)(ws + TKW_OFF + (size_t)b * 16) = wv;
    }
  }
}

// ---------------- main fused: GEMM1 -> GELU -> reg-GEMM2 -> reduce -> softmax
// BM=128 s x BN=256 n; 2048 blocks (XCD-chunked, expert-fast), 512 threads,
// 8 waves = 4 n-quarters (wnb) x 2 sample-halves (wsb); wave tile 64n x 64s.
// k-loop identical to r8/r10/r12 (best known). GEMM2 in registers; w2 B-frags
// direct from L2. NO market fusion (r13 lesson: per-thread tki/tkw loads +
// 655K atomics on the block tail cost +18us vs a 4us k_market dispatch).
// LDS: W dbuf 2x16K @0 ; X dbuf 2x8K @32768 ; partials 32K @0 (overlay). 49152 B.
// launch_bounds(512,4): allocator not pinched (r11 lesson: 85-reg cap -> spill).
// Softmax max-pass skipped (|logit| < ~1, exp2 safe).
__global__ __launch_bounds__(512, 4) void k_moe(const char* __restrict__ ws,
                                                const float* __restrict__ b2g,
                                                float* __restrict__ out) {
  __shared__ __align__(16) char smem[49152];
  const int lin = blockIdx.x;
  const int e = (lin >> 3) & 15;                 // expert-fast within an XCD chunk
  const int mt = (lin & 7) * 16 + (lin >> 7);    // each XCD owns 16 contiguous mtiles
  const int m0 = mt * 128;
  const int t = threadIdx.x;
  const int wid = t >> 6, l = t & 63;
  const int lq = l >> 4, lr = l & 15;
  const int wnb = wid >> 1;   // n-quarter 0..3 (64 n each)
  const int wsb = wid & 1;    // sample-half 0..1 (64 samples each)

  const uint16_t* xk = (const uint16_t*)(ws + XK_OFF) + (size_t)mt * 32768;   // [kt][128 s][32 k]
  const uint16_t* w1km = (const uint16_t*)(ws + W1T_OFF) + (size_t)e * 65536; // [kt][256 n][32 k]
  const uint16_t* w2t = (const uint16_t*)(ws + W2T_OFF) + (size_t)e * 4096;
  const float* b1p = (const float*)(ws + B1P_OFF) + e * 256;

  // staging source permutation: LDS 16B-unit u -> row 2p+hf, k-slot (sl^(p&3))
  const int pn = t >> 3, hf = (t >> 2) & 1, sl = t & 3;
  const int srcoff = (2 * pn + hf) * 32 + ((sl ^ (pn & 3)) * 8);
  const uint16_t* sW = w1km + srcoff;   // + kt*8192 ; second half + 4096
  const uint16_t* sX = xk + srcoff;     // + kt*4096

  // prologue: kt=0 W (16K) + X (8K) into buf0
  gl_lds16(sW, smem + wid * 1024);
  gl_lds16(sW + 4096, smem + 8192 + wid * 1024);
  gl_lds16(sX, smem + 32768 + wid * 1024);

  // fragment LDS offsets: row r -> p=r>>1 (pair), byte = p*128 + (r&1)*64 + ((lq^(p&3))<<4)
  const int pr = lr >> 1;
  const int fsw = (lr & 1) * 64 + ((lq ^ (pr & 3)) << 4);
  const int aoffb = (wnb * 32 + pr) * 128 + fsw;            // + buf*16384 + mi*1024
  const int xoffb = (wsb * 32 + pr) * 128 + fsw;            // + 32768 + buf*8192 + nj*1024

  f32x4 zz = {0.f, 0.f, 0.f, 0.f};
  f32x4 acc[4][4];  // [mi: n][nj: sample]
#pragma unroll
  for (int mi = 0; mi < 4; ++mi)
#pragma unroll
    for (int nj = 0; nj < 4; ++nj) acc[mi][nj] = zz;

  __syncthreads();
#pragma unroll
  for (int kt = 0; kt < 8; ++kt) {
    const int buf = kt & 1;
    // STAGE next kt first: reads+MFMA below cover the DMA before the drain
    if (kt < 7) {
      const uint16_t* a = sW + (kt + 1) * 8192;
      char* dW = smem + (buf ^ 1) * 16384 + wid * 1024;
      gl_lds16(a, dW);
      gl_lds16(a + 4096, dW + 8192);
      gl_lds16(sX + (kt + 1) * 4096, smem + 32768 + (buf ^ 1) * 8192 + wid * 1024);
    }
    bf16x8 af[4], xf[4];
#pragma unroll
    for (int mi = 0; mi < 4; ++mi)
      af[mi] = *(const bf16x8*)(smem + buf * 16384 + aoffb + mi * 1024);
#pragma unroll
    for (int nj = 0; nj < 4; ++nj)
      xf[nj] = *(const bf16x8*)(smem + 32768 + buf * 8192 + xoffb + nj * 1024);
    __builtin_amdgcn_s_setprio(1);
#pragma unroll
    for (int mi = 0; mi < 4; ++mi)
#pragma unroll
      for (int nj = 0; nj < 4; ++nj)
        acc[mi][nj] = __builtin_amdgcn_mfma_f32_16x16x32_bf16(af[mi], xf[nj], acc[mi][nj], 0, 0, 0);
    __builtin_amdgcn_s_setprio(0);
    __syncthreads();  // next tile landed; all reads of buf done
  }

  // w2 B-fragments DIRECT from L2: lane -> w2t[c=lr][wnb*64 + mi*16 + lq*4 .. +3]
  const uint16_t* w2l = w2t + lr * 256 + wnb * 64 + lq * 4;
  uint2 w2f[4];
#pragma unroll
  for (int mi = 0; mi < 4; ++mi)
    w2f[mi] = *(const uint2*)(w2l + mi * 16);
  uint4 ub0 = {w2f[0].x, w2f[0].y, w2f[1].x, w2f[1].y};  // k-frag for mi 0,1
  uint4 ub1 = {w2f[2].x, w2f[2].y, w2f[3].x, w2f[3].y};  // k-frag for mi 2,3

  float4 bn[4];
#pragma unroll
  for (int mi = 0; mi < 4; ++mi)
    bn[mi] = *(const float4*)(b1p + wnb * 64 + mi * 16 + lq * 4);

  // GELU in regs -> packed A-frags -> 2 MFMAs per nj (64n partial of D[s][c])
  f32x4 acc2[4];
#pragma unroll
  for (int nj = 0; nj < 4; ++nj) {
    uint32_t pk[8];
#pragma unroll
    for (int mi = 0; mi < 4; ++mi) {
      float g0 = gelu_f(acc[mi][nj][0] + bn[mi].x);
      float g1 = gelu_f(acc[mi][nj][1] + bn[mi].y);
      float g2 = gelu_f(acc[mi][nj][2] + bn[mi].z);
      float g3 = gelu_f(acc[mi][nj][3] + bn[mi].w);
      pk[mi * 2] = cvt_pk_bf16(g0, g1);
      pk[mi * 2 + 1] = cvt_pk_bf16(g2, g3);
    }
    uint4 ua0 = {pk[0], pk[1], pk[2], pk[3]};
    uint4 ua1 = {pk[4], pk[5], pk[6], pk[7]};
    f32x4 a2 = zz;
    a2 = __builtin_amdgcn_mfma_f32_16x16x32_bf16(__builtin_bit_cast(bf16x8, ua0),
                                                 __builtin_bit_cast(bf16x8, ub0), a2, 0, 0, 0);
    a2 = __builtin_amdgcn_mfma_f32_16x16x32_bf16(__builtin_bit_cast(bf16x8, ua1),
                                                 __builtin_bit_cast(bf16x8, ub1), a2, 0, 0, 0);
    acc2[nj] = a2;
  }

  // partial exchange @0 (overlays W dbuf): [g = wsb*4+nj][wnb][16 s][16 c] f32
  const int pswz = (lq ^ ((lr >> 1) & 3)) << 4;
  {
    const int pbase = wnb * 1024 + lr * 64 + pswz;
#pragma unroll
    for (int nj = 0; nj < 4; ++nj)
      *(f32x4*)(smem + pbase + (wsb * 4 + nj) * 4096) = acc2[nj];
  }
  __syncthreads();

  // reduce own group g = wsb*4+wnb over the 4 wnb-partials; softmax (no max pass:
  // |logit| < ~1); store all_probs
  {
    const int rbase = (wsb * 4 + wnb) * 4096 + lr * 64 + pswz;
    f32x4 r0 = *(const f32x4*)(smem + rbase);
    f32x4 r1 = *(const f32x4*)(smem + rbase + 1024);
    f32x4 r2 = *(const f32x4*)(smem + rbase + 2048);
    f32x4 r3 = *(const f32x4*)(smem + rbase + 3072);
    f32x4 tot;
#pragma unroll
    for (int j = 0; j < 4; ++j) tot[j] = (r0[j] + r1[j]) + (r2[j] + r3[j]);

    const int c = lr;
    float bias2 = (c < 10) ? b2g[e * 10 + c] : 0.0f;
#pragma unroll
    for (int rg = 0; rg < 4; ++rg) {
      float logit = tot[rg] + bias2;
      float ex = (c < 10) ? __builtin_amdgcn_exp2f(logit * LOG2E) : 0.0f;
      float sm = ex;
#pragma unroll
      for (int off = 1; off < 16; off <<= 1) sm += __shfl_xor(sm, off);
      if (c < 10) {
        float pr_ = ex * __builtin_amdgcn_rcpf(sm);
        size_t row = (size_t)e * 16384 + (m0 + wsb * 64 + wnb * 16 + lq * 4 + rg);
        out[APROBS_OFF + row * 10 + c] = pr_;
      }
    }
  }
}

// ---------------- market_probs = sum_k w_k * all_probs[idx_k, b, :] ----------------
__global__ __launch_bounds__(256) void k_market(const char* __restrict__ ws,
                                                float* __restrict__ out) {
  const int b = blockIdx.x * 256 + threadIdx.x;
  int4 id = *(const int4*)(ws + TKI_OFF + (size_t)b * 16);
  float4 wv = *(const float4*)(ws + TKW_OFF + (size_t)b * 16);
  const int ids[4] = {id.x, id.y, id.z, id.w};
  const float wss[4] = {wv.x, wv.y, wv.z, wv.w};
  float m[10];
#pragma unroll
  for (int c = 0; c < 10; ++c) m[c] = 0.f;
#pragma unroll
  for (int k = 0; k < 4; ++k) {
    const float* ap = out + APROBS_OFF + ((size_t)ids[k] * 16384 + b) * 10;
#pragma unroll
    for (int c = 0; c < 10; ++c) m[c] += wss[k] * ap[c];
  }
#pragma unroll
  for (int c = 0; c < 10; ++c) out[(size_t)b * 10 + c] = m[c];
}

extern "C" void kernel_launch(void* const* d_in, const int* in_sizes, int n_in,
                              void* d_out, int out_size, void* d_ws, size_t ws_size,
                              hipStream_t stream) {
  (void)in_sizes; (void)n_in; (void)out_size; (void)ws_size;
  const float* feat = (const float*)d_in[0];
  const float* rw   = (const float*)d_in[1];
  const float* rb   = (const float*)d_in[2];
  const float* ln_g = (const float*)d_in[3];
  const float* ln_b = (const float*)d_in[4];
  const float* w1   = (const float*)d_in[5];
  const float* b1   = (const float*)d_in[6];
  const float* w2   = (const float*)d_in[7];
  const float* b2   = (const float*)d_in[8];
  float* out = (float*)d_out;
  char* ws = (char*)d_ws;

  hipLaunchKernelGGL(k_pre, dim3(4368), dim3(256), 0, stream,
                     feat, rw, rb, ln_g, ln_b, b1, w1, w2, out, ws);
  hipLaunchKernelGGL(k_moe, dim3(2048), dim3(512), 0, stream, ws, b2, out);
  hipLaunchKernelGGL(k_market, dim3(64), dim3(256), 0, stream, ws, out);
}